// Round 4
// baseline (165.554 us; speedup 1.0000x reference)
//
#include <hip/hip_runtime.h>
#include <hip/hip_bf16.h>
#include <math.h>

// Problem constants
#define Bc 4
#define Nc 1024
#define Ec 1024
#define Hc 16
#define Dc 64
#define Mc 4096                    // B*N rows
#define OUT0_ELEMS 4194304         // B*H*N*D
#define ATTN_ELEMS 67108864ULL     // B*H*N*N floats
#define SCRATCH_OFF 58720256       // float offset into attn region for bf16 scratch

typedef __attribute__((ext_vector_type(4))) float f32x4;
typedef __attribute__((ext_vector_type(16))) float f32x16;
typedef __attribute__((ext_vector_type(8))) short s16x8;

// Hardware bf16 convert (compiler pairs into v_cvt_pk_bf16_f32)
__device__ __forceinline__ short f2bf(float f) {
    union { __bf16 h; short s; } c; c.h = (__bf16)f; return c.s;
}

// async global->LDS, 16B per lane; LDS dest = base + lane*16 (wave-linear)
typedef const __attribute__((address_space(1))) char gch;
typedef __attribute__((address_space(3))) char lch;
__device__ __forceinline__ void gload16(const short* g, short* l) {
    __builtin_amdgcn_global_load_lds((gch*)g, (lch*)l, 16, 0, 0);
}

// ---------------------------------------------------------------------------
// fp32 -> bf16 pre-pass for X{q,k,v} (4M elems each) and W{q,k,v} (1M each).
// dst layout: [Xq | Xk | Xv | Wq | Wk | Wv]
// ---------------------------------------------------------------------------
__global__ __launch_bounds__(256)
void cvt_kernel(const float* __restrict__ xq, const float* __restrict__ xk,
                const float* __restrict__ xv, const float* __restrict__ wq,
                const float* __restrict__ wk, const float* __restrict__ wv,
                short* __restrict__ dst)
{
    const int which = blockIdx.y;
    const float* src; size_t n, off;
    switch (which) {
      case 0:  src = xq; n = 4194304; off = 0;        break;
      case 1:  src = xk; n = 4194304; off = 4194304;  break;
      case 2:  src = xv; n = 4194304; off = 8388608;  break;
      case 3:  src = wq; n = 1048576; off = 12582912; break;
      case 4:  src = wk; n = 1048576; off = 13631488; break;
      default: src = wv; n = 1048576; off = 14680064; break;
    }
    const size_t i = ((size_t)blockIdx.x * 256 + threadIdx.x) * 8;
    if (i >= n) return;
    f32x4 a = *(const f32x4*)(src + i);
    f32x4 b = *(const f32x4*)(src + i + 4);
    s16x8 o;
    o[0] = f2bf(a[0]); o[1] = f2bf(a[1]); o[2] = f2bf(a[2]); o[3] = f2bf(a[3]);
    o[4] = f2bf(b[0]); o[5] = f2bf(b[1]); o[6] = f2bf(b[2]); o[7] = f2bf(b[3]);
    *(s16x8*)(dst + off + i) = o;
}

// ---------------------------------------------------------------------------
// Projection GEMM, m97 structure: bf16 inputs, 128x128 tile, BK=64,
// global_load_lds(16B) staging into linear LDS [128][64], 4 waves (2x2),
// 4x4 frags of 16x16x32 MFMA. sel 0->Q(bf16 ws), 1->K(bf16 ws), 2->V(fp32 out).
// ---------------------------------------------------------------------------
__global__ __launch_bounds__(256)
void proj_kernel(const short* __restrict__ xall, const short* __restrict__ wall,
                 const float* __restrict__ bq, const float* __restrict__ bk,
                 const float* __restrict__ bv,
                 short* __restrict__ qws, short* __restrict__ kws,
                 float* __restrict__ vout)
{
    const int sel = blockIdx.z;
    const short* X = xall + (size_t)sel * 4194304;
    const short* W = wall + (size_t)sel * 1048576;
    const float* bias = (sel == 0) ? bq : (sel == 1) ? bk : bv;

    __shared__ __align__(16) short lA[128 * 64];
    __shared__ __align__(16) short lB[128 * 64];

    const int t    = threadIdx.x;
    const int lane = t & 63;
    const int w    = t >> 6;
    const int wr   = w >> 1, wc = w & 1;      // 2x2 wave grid, 64x64 each
    const int li   = lane & 15, g = lane >> 4;
    const int bm   = blockIdx.x * 128;
    const int bn   = blockIdx.y * 128;

    // staging: lane covers row += lane>>3, col = (lane&7)*8 shorts
    const int srow = lane >> 3;
    const int scol = (lane & 7) * 8;
    const short* Xs = X + (size_t)bm * Ec + scol;
    const short* Ws = W + (size_t)bn * Ec + scol;

    f32x4 acc[4][4];
#pragma unroll
    for (int i = 0; i < 4; ++i)
#pragma unroll
        for (int j = 0; j < 4; ++j)
            acc[i][j] = (f32x4){0.f, 0.f, 0.f, 0.f};

    for (int kt = 0; kt < 16; ++kt) {
        const int kb = kt * 64;
        // ---- stage A and B tiles: 8 x global_load_lds_dwordx4 ----
#pragma unroll
        for (int j = 0; j < 4; ++j) {
            const int rbase = j * 32 + w * 8;
            gload16(Xs + (size_t)(rbase + srow) * Ec + kb, &lA[rbase * 64]);
            gload16(Ws + (size_t)(rbase + srow) * Ec + kb, &lB[rbase * 64]);
        }
        __syncthreads();

        // ---- MFMA: two K=32 sub-steps ----
#pragma unroll
        for (int s = 0; s < 2; ++s) {
            s16x8 aF[4], bF[4];
#pragma unroll
            for (int mt = 0; mt < 4; ++mt)
                aF[mt] = *(const s16x8*)&lA[(wr * 64 + mt * 16 + li) * 64 + s * 32 + g * 8];
#pragma unroll
            for (int nt = 0; nt < 4; ++nt)
                bF[nt] = *(const s16x8*)&lB[(wc * 64 + nt * 16 + li) * 64 + s * 32 + g * 8];
#pragma unroll
            for (int mt = 0; mt < 4; ++mt)
#pragma unroll
                for (int nt = 0; nt < 4; ++nt)
                    acc[mt][nt] = __builtin_amdgcn_mfma_f32_16x16x32_bf16(
                        aF[mt], bF[nt], acc[mt][nt], 0, 0, 0);
        }
        __syncthreads();
    }

    // ---- epilogue: bias add + head-split scatter ----
    short* dstBF = (sel == 0) ? qws : kws;
#pragma unroll
    for (int nt = 0; nt < 4; ++nt) {
        const int col = bn + wc * 64 + nt * 16 + li;
        const float bcol = bias[col];
        const int h = col >> 6, d = col & 63;
#pragma unroll
        for (int mt = 0; mt < 4; ++mt) {
#pragma unroll
            for (int r = 0; r < 4; ++r) {
                const int row = bm + wr * 64 + mt * 16 + g * 4 + r;
                const int bb = row >> 10, n = row & 1023;
                const size_t off = ((size_t)(bb * Hc + h) * Nc + n) * Dc + d;
                const float val = acc[mt][nt][r] + bcol;
                if (sel == 2)
                    vout[off] = val;
                else
                    dstBF[off] = f2bf(val);
            }
        }
    }
}

// ---------------------------------------------------------------------------
// Scores + softmax, 32x32 MFMA (UNCHANGED from round 3).
// ---------------------------------------------------------------------------
__global__ __launch_bounds__(256, 2)
void attn_kernel(const short* __restrict__ qws, const short* __restrict__ kws,
                 float* __restrict__ attnOut)
{
    const int rb = blockIdx.x;   // 0..31 (32-row block)
    const int bh = blockIdx.y;   // 0..63 (b*H + h)
    const int t  = threadIdx.x;
    const int w  = t >> 6;
    const int lane = t & 63;
    const int li = lane & 31;
    const int hi = lane >> 5;

    const short* Qb = qws + (size_t)bh * (Nc * Dc);
    const short* Kb = kws + (size_t)bh * (Nc * Dc);

    s16x8 qF[4];
    {
        const short* qp = Qb + (size_t)(rb * 32 + li) * Dc + hi * 8;
#pragma unroll
        for (int s = 0; s < 4; ++s)
            qF[s] = *(const s16x8*)(qp + s * 16);
    }

    f32x16 acc[8];
#pragma unroll
    for (int i = 0; i < 8; ++i) acc[i] = (f32x16)(0.f);

    const int colbase = w * 256;
#pragma unroll
    for (int ct = 0; ct < 8; ++ct) {
        const short* kp = Kb + (size_t)(colbase + ct * 32 + li) * Dc + hi * 8;
#pragma unroll
        for (int s = 0; s < 4; ++s) {
            s16x8 kf = *(const s16x8*)(kp + s * 16);
            acc[ct] = __builtin_amdgcn_mfma_f32_32x32x16_bf16(qF[s], kf, acc[ct], 0, 0, 0);
        }
    }

    float mx[16];
#pragma unroll
    for (int r = 0; r < 16; ++r) {
        float m = acc[0][r];
#pragma unroll
        for (int ct = 1; ct < 8; ++ct) m = fmaxf(m, acc[ct][r]);
#pragma unroll
        for (int off = 1; off < 32; off <<= 1)
            m = fmaxf(m, __shfl_xor(m, off));
        mx[r] = m;
    }

    __shared__ float red[4][32];
    if (li == 0) {
#pragma unroll
        for (int r = 0; r < 16; ++r)
            red[w][(r & 3) + 8 * (r >> 2) + 4 * hi] = mx[r];
    }
    __syncthreads();
    const float c = 1.44269504f / 32.0f;   // log2(e)/SCALE, SCALE = 32
#pragma unroll
    for (int r = 0; r < 16; ++r) {
        const int row = (r & 3) + 8 * (r >> 2) + 4 * hi;
        float m = fmaxf(fmaxf(red[0][row], red[1][row]),
                        fmaxf(red[2][row], red[3][row]));
        mx[r] = -m * c;
    }
    __syncthreads();

    float sm[16];
#pragma unroll
    for (int r = 0; r < 16; ++r) sm[r] = 0.f;
#pragma unroll
    for (int ct = 0; ct < 8; ++ct) {
#pragma unroll
        for (int r = 0; r < 16; ++r) {
            float p = __builtin_amdgcn_exp2f(fmaf(acc[ct][r], c, mx[r]));
            acc[ct][r] = p;
            sm[r] += p;
        }
    }
#pragma unroll
    for (int r = 0; r < 16; ++r) {
#pragma unroll
        for (int off = 1; off < 32; off <<= 1)
            sm[r] += __shfl_xor(sm[r], off);
    }
    if (li == 0) {
#pragma unroll
        for (int r = 0; r < 16; ++r)
            red[w][(r & 3) + 8 * (r >> 2) + 4 * hi] = sm[r];
    }
    __syncthreads();
#pragma unroll
    for (int r = 0; r < 16; ++r) {
        const int row = (r & 3) + 8 * (r >> 2) + 4 * hi;
        sm[r] = 1.0f / (red[0][row] + red[1][row] + red[2][row] + red[3][row]);
    }

    float* outp = attnOut + (size_t)bh * (Nc * Nc) + (size_t)(rb * 32) * Nc;
#pragma unroll
    for (int ct = 0; ct < 8; ++ct) {
        const int col = colbase + ct * 32 + li;
#pragma unroll
        for (int r = 0; r < 16; ++r) {
            const int row = (r & 3) + 8 * (r >> 2) + 4 * hi;
            outp[(size_t)row * Nc + col] = acc[ct][r] * sm[r];
        }
    }
}

extern "C" void kernel_launch(void* const* d_in, const int* in_sizes, int n_in,
                              void* d_out, int out_size, void* d_ws, size_t ws_size,
                              hipStream_t stream) {
    const float* q  = (const float*)d_in[0];
    const float* k  = (const float*)d_in[1];
    const float* v  = (const float*)d_in[2];
    const float* Wq = (const float*)d_in[3];
    const float* bq = (const float*)d_in[4];
    const float* Wk = (const float*)d_in[5];
    const float* bk = (const float*)d_in[6];
    const float* Wv = (const float*)d_in[7];
    const float* bv = (const float*)d_in[8];

    float* out0 = (float*)d_out;                      // (B,H,N,D) fp32
    float* attn = (float*)d_out + OUT0_ELEMS;         // (B,H,N,N) fp32

    // bf16 scratch in the TAIL of the attn region: proj reads it, then
    // attn_kernel overwrites the whole region. 15M shorts = 30 MB <= 32 MB.
    short* s16  = (short*)(attn + SCRATCH_OFF);
    short* xall = s16;                                // Xq|Xk|Xv bf16
    short* wall = s16 + 12582912;                     // Wq|Wk|Wv bf16

    short* qws = (short*)d_ws;                        // bf16 Q [b][h][n][d]
    short* kws = qws + (size_t)Mc * Ec;               // bf16 K [b][h][n][d]

    cvt_kernel<<<dim3(2048, 6), 256, 0, stream>>>(q, k, v, Wq, Wk, Wv, s16);
    proj_kernel<<<dim3(32, 8, 3), 256, 0, stream>>>(
        xall, wall, bq, bk, bv, qws, kws, out0);
    attn_kernel<<<dim3(32, 64), 256, 0, stream>>>(qws, kws, attn);
}

// Round 5
// 155.552 us; speedup vs baseline: 1.0643x; 1.0643x over previous
//
#include <hip/hip_runtime.h>
#include <hip/hip_bf16.h>
#include <math.h>

// Problem constants
#define Bc 4
#define Nc 1024
#define Ec 1024
#define Hc 16
#define Dc 64
#define Mc 4096                    // B*N rows
#define OUT0_ELEMS 4194304         // B*H*N*D
#define ATTN_ELEMS 67108864ULL     // B*H*N*N floats
#define SCRATCH_OFF 58720256       // float offset into attn region for bf16 scratch

typedef __attribute__((ext_vector_type(4))) float f32x4;
typedef __attribute__((ext_vector_type(16))) float f32x16;
typedef __attribute__((ext_vector_type(8))) short s16x8;

// Hardware bf16 convert (compiler pairs into v_cvt_pk_bf16_f32)
__device__ __forceinline__ short f2bf(float f) {
    union { __bf16 h; short s; } c; c.h = (__bf16)f; return c.s;
}

// async global->LDS, 16B per lane; LDS dest = base + lane*16 (wave-linear)
typedef const __attribute__((address_space(1))) char gch;
typedef __attribute__((address_space(3))) char lch;
__device__ __forceinline__ void gload16(const short* g, short* l) {
    __builtin_amdgcn_global_load_lds((gch*)g, (lch*)l, 16, 0, 0);
}

// ---------------------------------------------------------------------------
// fp32 -> bf16 pre-pass (UNCHANGED from round 4).
// ---------------------------------------------------------------------------
__global__ __launch_bounds__(256)
void cvt_kernel(const float* __restrict__ xq, const float* __restrict__ xk,
                const float* __restrict__ xv, const float* __restrict__ wq,
                const float* __restrict__ wk, const float* __restrict__ wv,
                short* __restrict__ dst)
{
    const int which = blockIdx.y;
    const float* src; size_t n, off;
    switch (which) {
      case 0:  src = xq; n = 4194304; off = 0;        break;
      case 1:  src = xk; n = 4194304; off = 4194304;  break;
      case 2:  src = xv; n = 4194304; off = 8388608;  break;
      case 3:  src = wq; n = 1048576; off = 12582912; break;
      case 4:  src = wk; n = 1048576; off = 13631488; break;
      default: src = wv; n = 1048576; off = 14680064; break;
    }
    const size_t i = ((size_t)blockIdx.x * 256 + threadIdx.x) * 8;
    if (i >= n) return;
    f32x4 a = *(const f32x4*)(src + i);
    f32x4 b = *(const f32x4*)(src + i + 4);
    s16x8 o;
    o[0] = f2bf(a[0]); o[1] = f2bf(a[1]); o[2] = f2bf(a[2]); o[3] = f2bf(a[3]);
    o[4] = f2bf(b[0]); o[5] = f2bf(b[1]); o[6] = f2bf(b[2]); o[7] = f2bf(b[3]);
    *(s16x8*)(dst + off + i) = o;
}

// ---------------------------------------------------------------------------
// Projection GEMM, m97 structure (UNCHANGED from round 4).
// ---------------------------------------------------------------------------
__global__ __launch_bounds__(256)
void proj_kernel(const short* __restrict__ xall, const short* __restrict__ wall,
                 const float* __restrict__ bq, const float* __restrict__ bk,
                 const float* __restrict__ bv,
                 short* __restrict__ qws, short* __restrict__ kws,
                 float* __restrict__ vout)
{
    const int sel = blockIdx.z;
    const short* X = xall + (size_t)sel * 4194304;
    const short* W = wall + (size_t)sel * 1048576;
    const float* bias = (sel == 0) ? bq : (sel == 1) ? bk : bv;

    __shared__ __align__(16) short lA[128 * 64];
    __shared__ __align__(16) short lB[128 * 64];

    const int t    = threadIdx.x;
    const int lane = t & 63;
    const int w    = t >> 6;
    const int wr   = w >> 1, wc = w & 1;
    const int li   = lane & 15, g = lane >> 4;
    const int bm   = blockIdx.x * 128;
    const int bn   = blockIdx.y * 128;

    const int srow = lane >> 3;
    const int scol = (lane & 7) * 8;
    const short* Xs = X + (size_t)bm * Ec + scol;
    const short* Ws = W + (size_t)bn * Ec + scol;

    f32x4 acc[4][4];
#pragma unroll
    for (int i = 0; i < 4; ++i)
#pragma unroll
        for (int j = 0; j < 4; ++j)
            acc[i][j] = (f32x4){0.f, 0.f, 0.f, 0.f};

    for (int kt = 0; kt < 16; ++kt) {
        const int kb = kt * 64;
#pragma unroll
        for (int j = 0; j < 4; ++j) {
            const int rbase = j * 32 + w * 8;
            gload16(Xs + (size_t)(rbase + srow) * Ec + kb, &lA[rbase * 64]);
            gload16(Ws + (size_t)(rbase + srow) * Ec + kb, &lB[rbase * 64]);
        }
        __syncthreads();

#pragma unroll
        for (int s = 0; s < 2; ++s) {
            s16x8 aF[4], bF[4];
#pragma unroll
            for (int mt = 0; mt < 4; ++mt)
                aF[mt] = *(const s16x8*)&lA[(wr * 64 + mt * 16 + li) * 64 + s * 32 + g * 8];
#pragma unroll
            for (int nt = 0; nt < 4; ++nt)
                bF[nt] = *(const s16x8*)&lB[(wc * 64 + nt * 16 + li) * 64 + s * 32 + g * 8];
#pragma unroll
            for (int mt = 0; mt < 4; ++mt)
#pragma unroll
                for (int nt = 0; nt < 4; ++nt)
                    acc[mt][nt] = __builtin_amdgcn_mfma_f32_16x16x32_bf16(
                        aF[mt], bF[nt], acc[mt][nt], 0, 0, 0);
        }
        __syncthreads();
    }

    short* dstBF = (sel == 0) ? qws : kws;
#pragma unroll
    for (int nt = 0; nt < 4; ++nt) {
        const int col = bn + wc * 64 + nt * 16 + li;
        const float bcol = bias[col];
        const int h = col >> 6, d = col & 63;
#pragma unroll
        for (int mt = 0; mt < 4; ++mt) {
#pragma unroll
            for (int r = 0; r < 4; ++r) {
                const int row = bm + wr * 64 + mt * 16 + g * 4 + r;
                const int bb = row >> 10, n = row & 1023;
                const size_t off = ((size_t)(bb * Hc + h) * Nc + n) * Dc + d;
                const float val = acc[mt][nt][r] + bcol;
                if (sel == 2)
                    vout[off] = val;
                else
                    dstBF[off] = f2bf(val);
            }
        }
    }
}

// ---------------------------------------------------------------------------
// Scores + softmax, 32x32 MFMA. Round-5 changes:
//  (1) 1D grid, XCD-clustered: all 32 row-blocks of a head map to the same
//      XCD (bid%8 == bh>>3), heads processed sequentially per XCD -> K stays
//      L2-resident (working set ~384 KB vs 4 MB L2).
//  (2) Nontemporal attn stores: don't evict K from L2 via write-allocate.
// ---------------------------------------------------------------------------
__global__ __launch_bounds__(256, 2)
void attn_kernel(const short* __restrict__ qws, const short* __restrict__ kws,
                 float* __restrict__ attnOut)
{
    const int bid = blockIdx.x;                 // 0..2047
    const int rb  = (bid >> 3) & 31;            // 32-row block
    const int bh  = ((bid & 7) << 3) | (bid >> 8);  // head: bid%8 == bh>>3
    const int t  = threadIdx.x;
    const int w  = t >> 6;
    const int lane = t & 63;
    const int li = lane & 31;
    const int hi = lane >> 5;

    const short* Qb = qws + (size_t)bh * (Nc * Dc);
    const short* Kb = kws + (size_t)bh * (Nc * Dc);

    s16x8 qF[4];
    {
        const short* qp = Qb + (size_t)(rb * 32 + li) * Dc + hi * 8;
#pragma unroll
        for (int s = 0; s < 4; ++s)
            qF[s] = *(const s16x8*)(qp + s * 16);
    }

    f32x16 acc[8];
#pragma unroll
    for (int i = 0; i < 8; ++i) acc[i] = (f32x16)(0.f);

    const int colbase = w * 256;
#pragma unroll
    for (int ct = 0; ct < 8; ++ct) {
        const short* kp = Kb + (size_t)(colbase + ct * 32 + li) * Dc + hi * 8;
#pragma unroll
        for (int s = 0; s < 4; ++s) {
            s16x8 kf = *(const s16x8*)(kp + s * 16);
            acc[ct] = __builtin_amdgcn_mfma_f32_32x32x16_bf16(qF[s], kf, acc[ct], 0, 0, 0);
        }
    }

    float mx[16];
#pragma unroll
    for (int r = 0; r < 16; ++r) {
        float m = acc[0][r];
#pragma unroll
        for (int ct = 1; ct < 8; ++ct) m = fmaxf(m, acc[ct][r]);
#pragma unroll
        for (int off = 1; off < 32; off <<= 1)
            m = fmaxf(m, __shfl_xor(m, off));
        mx[r] = m;
    }

    __shared__ float red[4][32];
    if (li == 0) {
#pragma unroll
        for (int r = 0; r < 16; ++r)
            red[w][(r & 3) + 8 * (r >> 2) + 4 * hi] = mx[r];
    }
    __syncthreads();
    const float c = 1.44269504f / 32.0f;   // log2(e)/SCALE, SCALE = 32
#pragma unroll
    for (int r = 0; r < 16; ++r) {
        const int row = (r & 3) + 8 * (r >> 2) + 4 * hi;
        float m = fmaxf(fmaxf(red[0][row], red[1][row]),
                        fmaxf(red[2][row], red[3][row]));
        mx[r] = -m * c;
    }
    __syncthreads();

    float sm[16];
#pragma unroll
    for (int r = 0; r < 16; ++r) sm[r] = 0.f;
#pragma unroll
    for (int ct = 0; ct < 8; ++ct) {
#pragma unroll
        for (int r = 0; r < 16; ++r) {
            float p = __builtin_amdgcn_exp2f(fmaf(acc[ct][r], c, mx[r]));
            acc[ct][r] = p;
            sm[r] += p;
        }
    }
#pragma unroll
    for (int r = 0; r < 16; ++r) {
#pragma unroll
        for (int off = 1; off < 32; off <<= 1)
            sm[r] += __shfl_xor(sm[r], off);
    }
    if (li == 0) {
#pragma unroll
        for (int r = 0; r < 16; ++r)
            red[w][(r & 3) + 8 * (r >> 2) + 4 * hi] = sm[r];
    }
    __syncthreads();
#pragma unroll
    for (int r = 0; r < 16; ++r) {
        const int row = (r & 3) + 8 * (r >> 2) + 4 * hi;
        sm[r] = 1.0f / (red[0][row] + red[1][row] + red[2][row] + red[3][row]);
    }

    // nontemporal stores: full 128B-line segments, no L2 write-allocate churn
    float* outp = attnOut + (size_t)bh * (Nc * Nc) + (size_t)(rb * 32) * Nc;
#pragma unroll
    for (int ct = 0; ct < 8; ++ct) {
        const int col = colbase + ct * 32 + li;
#pragma unroll
        for (int r = 0; r < 16; ++r) {
            const int row = (r & 3) + 8 * (r >> 2) + 4 * hi;
            __builtin_nontemporal_store(acc[ct][r] * sm[r],
                                        &outp[(size_t)row * Nc + col]);
        }
    }
}

extern "C" void kernel_launch(void* const* d_in, const int* in_sizes, int n_in,
                              void* d_out, int out_size, void* d_ws, size_t ws_size,
                              hipStream_t stream) {
    const float* q  = (const float*)d_in[0];
    const float* k  = (const float*)d_in[1];
    const float* v  = (const float*)d_in[2];
    const float* Wq = (const float*)d_in[3];
    const float* bq = (const float*)d_in[4];
    const float* Wk = (const float*)d_in[5];
    const float* bk = (const float*)d_in[6];
    const float* Wv = (const float*)d_in[7];
    const float* bv = (const float*)d_in[8];

    float* out0 = (float*)d_out;                      // (B,H,N,D) fp32
    float* attn = (float*)d_out + OUT0_ELEMS;         // (B,H,N,N) fp32

    // bf16 scratch in the TAIL of the attn region: proj reads it, then
    // attn_kernel overwrites the whole region. 15M shorts = 30 MB.
    short* s16  = (short*)(attn + SCRATCH_OFF);
    short* xall = s16;                                // Xq|Xk|Xv bf16
    short* wall = s16 + 12582912;                     // Wq|Wk|Wv bf16

    short* qws = (short*)d_ws;                        // bf16 Q [b][h][n][d]
    short* kws = qws + (size_t)Mc * Ec;               // bf16 K [b][h][n][d]

    cvt_kernel<<<dim3(2048, 6), 256, 0, stream>>>(q, k, v, Wq, Wk, Wv, s16);
    proj_kernel<<<dim3(32, 8, 3), 256, 0, stream>>>(
        xall, wall, bq, bk, bv, qws, kws, out0);
    attn_kernel<<<2048, 256, 0, stream>>>(qws, kws, attn);
}

// Round 6
// 143.057 us; speedup vs baseline: 1.1573x; 1.0873x over previous
//
#include <hip/hip_runtime.h>
#include <hip/hip_bf16.h>
#include <math.h>

// Problem constants
#define Bc 4
#define Nc 1024
#define Ec 1024
#define Hc 16
#define Dc 64
#define Mc 4096                    // B*N rows
#define OUT0_ELEMS 4194304         // B*H*N*D
#define ATTN_ELEMS 67108864ULL     // B*H*N*N floats
#define SCRATCH_OFF 58720256       // float offset into attn region for bf16 scratch

typedef __attribute__((ext_vector_type(4))) float f32x4;
typedef __attribute__((ext_vector_type(16))) float f32x16;
typedef __attribute__((ext_vector_type(8))) short s16x8;

// Hardware bf16 convert (compiler pairs into v_cvt_pk_bf16_f32)
__device__ __forceinline__ short f2bf(float f) {
    union { __bf16 h; short s; } c; c.h = (__bf16)f; return c.s;
}

// async global->LDS, 16B per lane; LDS dest = wave-uniform base + lane*16
typedef const __attribute__((address_space(1))) char gch;
typedef __attribute__((address_space(3))) char lch;
__device__ __forceinline__ void gload16(const short* g, short* l) {
    __builtin_amdgcn_global_load_lds((gch*)g, (lch*)l, 16, 0, 0);
}

// ---------------------------------------------------------------------------
// fp32 -> bf16 pre-pass (UNCHANGED).
// ---------------------------------------------------------------------------
__global__ __launch_bounds__(256)
void cvt_kernel(const float* __restrict__ xq, const float* __restrict__ xk,
                const float* __restrict__ xv, const float* __restrict__ wq,
                const float* __restrict__ wk, const float* __restrict__ wv,
                short* __restrict__ dst)
{
    const int which = blockIdx.y;
    const float* src; size_t n, off;
    switch (which) {
      case 0:  src = xq; n = 4194304; off = 0;        break;
      case 1:  src = xk; n = 4194304; off = 4194304;  break;
      case 2:  src = xv; n = 4194304; off = 8388608;  break;
      case 3:  src = wq; n = 1048576; off = 12582912; break;
      case 4:  src = wk; n = 1048576; off = 13631488; break;
      default: src = wv; n = 1048576; off = 14680064; break;
    }
    const size_t i = ((size_t)blockIdx.x * 256 + threadIdx.x) * 8;
    if (i >= n) return;
    f32x4 a = *(const f32x4*)(src + i);
    f32x4 b = *(const f32x4*)(src + i + 4);
    s16x8 o;
    o[0] = f2bf(a[0]); o[1] = f2bf(a[1]); o[2] = f2bf(a[2]); o[3] = f2bf(a[3]);
    o[4] = f2bf(b[0]); o[5] = f2bf(b[1]); o[6] = f2bf(b[2]); o[7] = f2bf(b[3]);
    *(s16x8*)(dst + off + i) = o;
}

// ---------------------------------------------------------------------------
// Projection GEMM, round-6: 2-phase double-buffered pipeline (catalog T3-min).
// BK=32, LDS = 2 bufs x ([128][32] A + [128][32] B) = 32 KB (occupancy kept).
// Per step: issue STAGE(next) FIRST, then ds_read+MFMA current, then one
// __syncthreads (vmcnt drain happens AFTER compute -> latency hidden).
// ---------------------------------------------------------------------------
__global__ __launch_bounds__(256)
void proj_kernel(const short* __restrict__ xall, const short* __restrict__ wall,
                 const float* __restrict__ bq, const float* __restrict__ bk,
                 const float* __restrict__ bv,
                 short* __restrict__ qws, short* __restrict__ kws,
                 float* __restrict__ vout)
{
    const int sel = blockIdx.z;
    const short* X = xall + (size_t)sel * 4194304;
    const short* W = wall + (size_t)sel * 1048576;
    const float* bias = (sel == 0) ? bq : (sel == 1) ? bk : bv;

    __shared__ __align__(16) short lA[2][128 * 32];
    __shared__ __align__(16) short lB[2][128 * 32];

    const int t    = threadIdx.x;
    const int lane = t & 63;
    const int w    = t >> 6;
    const int wr   = w >> 1, wc = w & 1;      // 2x2 wave grid, 64x64 each
    const int li   = lane & 15, g = lane >> 4;
    const int bm   = blockIdx.x * 128;
    const int bn   = blockIdx.y * 128;

    // staging: wave w covers rows [w*32, w*32+32); within a gload, lane
    // covers row j*16 + (lane>>2), col (lane&3)*8 shorts (16B). LDS dest is
    // wave-uniform base + lane*16 (linear) as gload_lds requires.
    const int sr = lane >> 2;                 // 0..15
    const int sc = (lane & 3) * 8;            // shorts
    const short* Xs = X + (size_t)(bm + w * 32) * Ec + sc;
    const short* Ws = W + (size_t)(bn + w * 32) * Ec + sc;

    f32x4 acc[4][4];
#pragma unroll
    for (int i = 0; i < 4; ++i)
#pragma unroll
        for (int j = 0; j < 4; ++j)
            acc[i][j] = (f32x4){0.f, 0.f, 0.f, 0.f};

#define STAGE(buf, kt)                                                        \
    {                                                                         \
        const int kb = (kt) * 32;                                             \
        _Pragma("unroll")                                                     \
        for (int j = 0; j < 2; ++j) {                                         \
            gload16(Xs + (size_t)(j * 16 + sr) * Ec + kb,                     \
                    &lA[buf][(w * 32 + j * 16) * 32]);                        \
            gload16(Ws + (size_t)(j * 16 + sr) * Ec + kb,                     \
                    &lB[buf][(w * 32 + j * 16) * 32]);                        \
        }                                                                     \
    }

    STAGE(0, 0);
    __syncthreads();

    for (int kt = 0; kt < 32; ++kt) {
        const int cur = kt & 1;
        if (kt < 31) STAGE(cur ^ 1, kt + 1);   // issue next-tile loads first

        s16x8 aF[4], bF[4];
#pragma unroll
        for (int mt = 0; mt < 4; ++mt)
            aF[mt] = *(const s16x8*)&lA[cur][(wr * 64 + mt * 16 + li) * 32 + g * 8];
#pragma unroll
        for (int nt = 0; nt < 4; ++nt)
            bF[nt] = *(const s16x8*)&lB[cur][(wc * 64 + nt * 16 + li) * 32 + g * 8];
#pragma unroll
        for (int mt = 0; mt < 4; ++mt)
#pragma unroll
            for (int nt = 0; nt < 4; ++nt)
                acc[mt][nt] = __builtin_amdgcn_mfma_f32_16x16x32_bf16(
                    aF[mt], bF[nt], acc[mt][nt], 0, 0, 0);

        __syncthreads();   // drains vmcnt (next buf ready) + lgkm (reads done)
    }
#undef STAGE

    // ---- epilogue: bias add + head-split scatter (unchanged) ----
    short* dstBF = (sel == 0) ? qws : kws;
#pragma unroll
    for (int nt = 0; nt < 4; ++nt) {
        const int col = bn + wc * 64 + nt * 16 + li;
        const float bcol = bias[col];
        const int h = col >> 6, d = col & 63;
#pragma unroll
        for (int mt = 0; mt < 4; ++mt) {
#pragma unroll
            for (int r = 0; r < 4; ++r) {
                const int row = bm + wr * 64 + mt * 16 + g * 4 + r;
                const int bb = row >> 10, n = row & 1023;
                const size_t off = ((size_t)(bb * Hc + h) * Nc + n) * Dc + d;
                const float val = acc[mt][nt][r] + bcol;
                if (sel == 2)
                    vout[off] = val;
                else
                    dstBF[off] = f2bf(val);
            }
        }
    }
}

// ---------------------------------------------------------------------------
// Scores + softmax, 32x32 MFMA (UNCHANGED from round 5: XCD-clustered grid,
// nontemporal full-line stores).
// ---------------------------------------------------------------------------
__global__ __launch_bounds__(256, 2)
void attn_kernel(const short* __restrict__ qws, const short* __restrict__ kws,
                 float* __restrict__ attnOut)
{
    const int bid = blockIdx.x;                 // 0..2047
    const int rb  = (bid >> 3) & 31;            // 32-row block
    const int bh  = ((bid & 7) << 3) | (bid >> 8);  // head: bid%8 == bh>>3
    const int t  = threadIdx.x;
    const int w  = t >> 6;
    const int lane = t & 63;
    const int li = lane & 31;
    const int hi = lane >> 5;

    const short* Qb = qws + (size_t)bh * (Nc * Dc);
    const short* Kb = kws + (size_t)bh * (Nc * Dc);

    s16x8 qF[4];
    {
        const short* qp = Qb + (size_t)(rb * 32 + li) * Dc + hi * 8;
#pragma unroll
        for (int s = 0; s < 4; ++s)
            qF[s] = *(const s16x8*)(qp + s * 16);
    }

    f32x16 acc[8];
#pragma unroll
    for (int i = 0; i < 8; ++i) acc[i] = (f32x16)(0.f);

    const int colbase = w * 256;
#pragma unroll
    for (int ct = 0; ct < 8; ++ct) {
        const short* kp = Kb + (size_t)(colbase + ct * 32 + li) * Dc + hi * 8;
#pragma unroll
        for (int s = 0; s < 4; ++s) {
            s16x8 kf = *(const s16x8*)(kp + s * 16);
            acc[ct] = __builtin_amdgcn_mfma_f32_32x32x16_bf16(qF[s], kf, acc[ct], 0, 0, 0);
        }
    }

    float mx[16];
#pragma unroll
    for (int r = 0; r < 16; ++r) {
        float m = acc[0][r];
#pragma unroll
        for (int ct = 1; ct < 8; ++ct) m = fmaxf(m, acc[ct][r]);
#pragma unroll
        for (int off = 1; off < 32; off <<= 1)
            m = fmaxf(m, __shfl_xor(m, off));
        mx[r] = m;
    }

    __shared__ float red[4][32];
    if (li == 0) {
#pragma unroll
        for (int r = 0; r < 16; ++r)
            red[w][(r & 3) + 8 * (r >> 2) + 4 * hi] = mx[r];
    }
    __syncthreads();
    const float c = 1.44269504f / 32.0f;   // log2(e)/SCALE, SCALE = 32
#pragma unroll
    for (int r = 0; r < 16; ++r) {
        const int row = (r & 3) + 8 * (r >> 2) + 4 * hi;
        float m = fmaxf(fmaxf(red[0][row], red[1][row]),
                        fmaxf(red[2][row], red[3][row]));
        mx[r] = -m * c;
    }
    __syncthreads();

    float sm[16];
#pragma unroll
    for (int r = 0; r < 16; ++r) sm[r] = 0.f;
#pragma unroll
    for (int ct = 0; ct < 8; ++ct) {
#pragma unroll
        for (int r = 0; r < 16; ++r) {
            float p = __builtin_amdgcn_exp2f(fmaf(acc[ct][r], c, mx[r]));
            acc[ct][r] = p;
            sm[r] += p;
        }
    }
#pragma unroll
    for (int r = 0; r < 16; ++r) {
#pragma unroll
        for (int off = 1; off < 32; off <<= 1)
            sm[r] += __shfl_xor(sm[r], off);
    }
    if (li == 0) {
#pragma unroll
        for (int r = 0; r < 16; ++r)
            red[w][(r & 3) + 8 * (r >> 2) + 4 * hi] = sm[r];
    }
    __syncthreads();
#pragma unroll
    for (int r = 0; r < 16; ++r) {
        const int row = (r & 3) + 8 * (r >> 2) + 4 * hi;
        sm[r] = 1.0f / (red[0][row] + red[1][row] + red[2][row] + red[3][row]);
    }

    float* outp = attnOut + (size_t)bh * (Nc * Nc) + (size_t)(rb * 32) * Nc;
#pragma unroll
    for (int ct = 0; ct < 8; ++ct) {
        const int col = colbase + ct * 32 + li;
#pragma unroll
        for (int r = 0; r < 16; ++r) {
            const int row = (r & 3) + 8 * (r >> 2) + 4 * hi;
            __builtin_nontemporal_store(acc[ct][r] * sm[r],
                                        &outp[(size_t)row * Nc + col]);
        }
    }
}

extern "C" void kernel_launch(void* const* d_in, const int* in_sizes, int n_in,
                              void* d_out, int out_size, void* d_ws, size_t ws_size,
                              hipStream_t stream) {
    const float* q  = (const float*)d_in[0];
    const float* k  = (const float*)d_in[1];
    const float* v  = (const float*)d_in[2];
    const float* Wq = (const float*)d_in[3];
    const float* bq = (const float*)d_in[4];
    const float* Wk = (const float*)d_in[5];
    const float* bk = (const float*)d_in[6];
    const float* Wv = (const float*)d_in[7];
    const float* bv = (const float*)d_in[8];

    float* out0 = (float*)d_out;                      // (B,H,N,D) fp32
    float* attn = (float*)d_out + OUT0_ELEMS;         // (B,H,N,N) fp32

    // bf16 scratch in the TAIL of the attn region: proj reads it, then
    // attn_kernel overwrites the whole region. 15M shorts = 30 MB.
    short* s16  = (short*)(attn + SCRATCH_OFF);
    short* xall = s16;                                // Xq|Xk|Xv bf16
    short* wall = s16 + 12582912;                     // Wq|Wk|Wv bf16

    short* qws = (short*)d_ws;                        // bf16 Q [b][h][n][d]
    short* kws = qws + (size_t)Mc * Ec;               // bf16 K [b][h][n][d]

    cvt_kernel<<<dim3(2048, 6), 256, 0, stream>>>(q, k, v, Wq, Wk, Wv, s16);
    proj_kernel<<<dim3(32, 8, 3), 256, 0, stream>>>(
        xall, wall, bq, bk, bv, qws, kws, out0);
    attn_kernel<<<2048, 256, 0, stream>>>(qws, kws, attn);
}

// Round 7
// 140.826 us; speedup vs baseline: 1.1756x; 1.0158x over previous
//
#include <hip/hip_runtime.h>
#include <hip/hip_bf16.h>
#include <math.h>

// Problem constants
#define Bc 4
#define Nc 1024
#define Ec 1024
#define Hc 16
#define Dc 64
#define Mc 4096                    // B*N rows
#define OUT0_ELEMS 4194304         // B*H*N*D
#define ATTN_ELEMS 67108864ULL     // B*H*N*N floats
#define SCRATCH_OFF 58720256       // float offset into attn region for bf16 scratch
#define NTK 32                     // K-tiles (BK=32) in proj

typedef __attribute__((ext_vector_type(4))) float f32x4;
typedef __attribute__((ext_vector_type(16))) float f32x16;
typedef __attribute__((ext_vector_type(8))) short s16x8;

// Hardware bf16 convert (compiler pairs into v_cvt_pk_bf16_f32)
__device__ __forceinline__ short f2bf(float f) {
    union { __bf16 h; short s; } c; c.h = (__bf16)f; return c.s;
}

// async global->LDS, 16B per lane; LDS dest = wave-uniform base + lane*16
typedef const __attribute__((address_space(1))) char gch;
typedef __attribute__((address_space(3))) char lch;
__device__ __forceinline__ void gload16(const short* g, short* l) {
    __builtin_amdgcn_global_load_lds((gch*)g, (lch*)l, 16, 0, 0);
}

// ---------------------------------------------------------------------------
// fp32 -> bf16 pre-pass (UNCHANGED).
// ---------------------------------------------------------------------------
__global__ __launch_bounds__(256)
void cvt_kernel(const float* __restrict__ xq, const float* __restrict__ xk,
                const float* __restrict__ xv, const float* __restrict__ wq,
                const float* __restrict__ wk, const float* __restrict__ wv,
                short* __restrict__ dst)
{
    const int which = blockIdx.y;
    const float* src; size_t n, off;
    switch (which) {
      case 0:  src = xq; n = 4194304; off = 0;        break;
      case 1:  src = xk; n = 4194304; off = 4194304;  break;
      case 2:  src = xv; n = 4194304; off = 8388608;  break;
      case 3:  src = wq; n = 1048576; off = 12582912; break;
      case 4:  src = wk; n = 1048576; off = 13631488; break;
      default: src = wv; n = 1048576; off = 14680064; break;
    }
    const size_t i = ((size_t)blockIdx.x * 256 + threadIdx.x) * 8;
    if (i >= n) return;
    f32x4 a = *(const f32x4*)(src + i);
    f32x4 b = *(const f32x4*)(src + i + 4);
    s16x8 o;
    o[0] = f2bf(a[0]); o[1] = f2bf(a[1]); o[2] = f2bf(a[2]); o[3] = f2bf(a[3]);
    o[4] = f2bf(b[0]); o[5] = f2bf(b[1]); o[6] = f2bf(b[2]); o[7] = f2bf(b[3]);
    *(s16x8*)(dst + off + i) = o;
}

// ---------------------------------------------------------------------------
// Projection GEMM, round-7: 3-buffer counted-vmcnt pipeline (T3/T4) +
// 16B-chunk XOR swizzle via pre-swizzled global source (T2, rule #21).
// BK=32; LDS = 3 x ([128][32] A + [128][32] B) = 48 KB -> 3 blocks/CU.
// Steady state per wave: 8 gloads outstanding; vmcnt(4) retires next tile.
// Swizzle: LDS slot (row, c') holds global chunk c = c' ^ ((row>>1)&3);
// fragment reads apply the same XOR -> 2-way bank aliasing (free).
// ---------------------------------------------------------------------------
__global__ __launch_bounds__(256)
void proj_kernel(const short* __restrict__ xall, const short* __restrict__ wall,
                 const float* __restrict__ bq, const float* __restrict__ bk,
                 const float* __restrict__ bv,
                 short* __restrict__ qws, short* __restrict__ kws,
                 float* __restrict__ vout)
{
    const int sel = blockIdx.z;
    const short* X = xall + (size_t)sel * 4194304;
    const short* W = wall + (size_t)sel * 1048576;
    const float* bias = (sel == 0) ? bq : (sel == 1) ? bk : bv;

    __shared__ __align__(16) short lA[3][128 * 32];
    __shared__ __align__(16) short lB[3][128 * 32];

    const int t    = threadIdx.x;
    const int lane = t & 63;
    const int w    = t >> 6;
    const int wr   = w >> 1, wc = w & 1;      // 2x2 wave grid, 64x64 each
    const int li   = lane & 15, g = lane >> 4;
    const int bm   = blockIdx.x * 128;
    const int bn   = blockIdx.y * 128;

    // staging: lane -> LDS slot (row = w*32 + j*16 + (lane>>2), chunk lane&3)
    const int sr = lane >> 2;                 // 0..15
    const int c_ = lane & 3;                  // 16B chunk within 64B row

    f32x4 acc[4][4];
#pragma unroll
    for (int i = 0; i < 4; ++i)
#pragma unroll
        for (int j = 0; j < 4; ++j)
            acc[i][j] = (f32x4){0.f, 0.f, 0.f, 0.f};

    // STAGE: 4 gloads/wave. Global source chunk pre-swizzled so that the
    // linear LDS write lands the XOR-swizzled layout.
#define STAGE(buf, kt)                                                        \
    {                                                                         \
        const int kb = (kt) * 32;                                             \
        _Pragma("unroll")                                                     \
        for (int j = 0; j < 2; ++j) {                                         \
            const int row = w * 32 + j * 16 + sr;                             \
            const int cg  = (c_ ^ ((row >> 1) & 3)) * 8;                      \
            gload16(X + (size_t)(bm + row) * Ec + kb + cg,                    \
                    &lA[buf][(w * 32 + j * 16) * 32]);                        \
            gload16(W + (size_t)(bn + row) * Ec + kb + cg,                    \
                    &lB[buf][(w * 32 + j * 16) * 32]);                        \
        }                                                                     \
    }

    STAGE(0, 0);
    STAGE(1, 1);
    asm volatile("s_waitcnt vmcnt(4)" ::: "memory");   // tile 0 staged
    __builtin_amdgcn_s_barrier();

    for (int kt = 0; kt < NTK; ++kt) {
        const int cur = kt % 3;
        if (kt + 2 < NTK) STAGE((kt + 2) % 3, kt + 2);  // prefetch 2 ahead

        // ---- compute tile kt (swizzled fragment reads) ----
        s16x8 aF[4], bF[4];
#pragma unroll
        for (int mt = 0; mt < 4; ++mt) {
            const int r = wr * 64 + mt * 16 + li;
            aF[mt] = *(const s16x8*)&lA[cur][r * 32 + ((g ^ ((r >> 1) & 3)) * 8)];
        }
#pragma unroll
        for (int nt = 0; nt < 4; ++nt) {
            const int r = wc * 64 + nt * 16 + li;
            bF[nt] = *(const s16x8*)&lB[cur][r * 32 + ((g ^ ((r >> 1) & 3)) * 8)];
        }
#pragma unroll
        for (int mt = 0; mt < 4; ++mt)
#pragma unroll
            for (int nt = 0; nt < 4; ++nt)
                acc[mt][nt] = __builtin_amdgcn_mfma_f32_16x16x32_bf16(
                    aF[mt], bF[nt], acc[mt][nt], 0, 0, 0);

        // ---- counted drain: next tile's 4 loads retired, deeper stay in flight
        if (kt + 2 < NTK) {
            asm volatile("s_waitcnt vmcnt(4)" ::: "memory");
        } else {
            asm volatile("s_waitcnt vmcnt(0)" ::: "memory");
        }
        __builtin_amdgcn_s_barrier();
    }
#undef STAGE

    // ---- epilogue: bias add + head-split scatter (unchanged) ----
    short* dstBF = (sel == 0) ? qws : kws;
#pragma unroll
    for (int nt = 0; nt < 4; ++nt) {
        const int col = bn + wc * 64 + nt * 16 + li;
        const float bcol = bias[col];
        const int h = col >> 6, d = col & 63;
#pragma unroll
        for (int mt = 0; mt < 4; ++mt) {
#pragma unroll
            for (int r = 0; r < 4; ++r) {
                const int row = bm + wr * 64 + mt * 16 + g * 4 + r;
                const int bb = row >> 10, n = row & 1023;
                const size_t off = ((size_t)(bb * Hc + h) * Nc + n) * Dc + d;
                const float val = acc[mt][nt][r] + bcol;
                if (sel == 2)
                    vout[off] = val;
                else
                    dstBF[off] = f2bf(val);
            }
        }
    }
}

// ---------------------------------------------------------------------------
// Scores + softmax, 32x32 MFMA (UNCHANGED: XCD-clustered grid, NT stores).
// ---------------------------------------------------------------------------
__global__ __launch_bounds__(256, 2)
void attn_kernel(const short* __restrict__ qws, const short* __restrict__ kws,
                 float* __restrict__ attnOut)
{
    const int bid = blockIdx.x;                 // 0..2047
    const int rb  = (bid >> 3) & 31;            // 32-row block
    const int bh  = ((bid & 7) << 3) | (bid >> 8);  // head: bid%8 == bh>>3
    const int t  = threadIdx.x;
    const int w  = t >> 6;
    const int lane = t & 63;
    const int li = lane & 31;
    const int hi = lane >> 5;

    const short* Qb = qws + (size_t)bh * (Nc * Dc);
    const short* Kb = kws + (size_t)bh * (Nc * Dc);

    s16x8 qF[4];
    {
        const short* qp = Qb + (size_t)(rb * 32 + li) * Dc + hi * 8;
#pragma unroll
        for (int s = 0; s < 4; ++s)
            qF[s] = *(const s16x8*)(qp + s * 16);
    }

    f32x16 acc[8];
#pragma unroll
    for (int i = 0; i < 8; ++i) acc[i] = (f32x16)(0.f);

    const int colbase = w * 256;
#pragma unroll
    for (int ct = 0; ct < 8; ++ct) {
        const short* kp = Kb + (size_t)(colbase + ct * 32 + li) * Dc + hi * 8;
#pragma unroll
        for (int s = 0; s < 4; ++s) {
            s16x8 kf = *(const s16x8*)(kp + s * 16);
            acc[ct] = __builtin_amdgcn_mfma_f32_32x32x16_bf16(qF[s], kf, acc[ct], 0, 0, 0);
        }
    }

    float mx[16];
#pragma unroll
    for (int r = 0; r < 16; ++r) {
        float m = acc[0][r];
#pragma unroll
        for (int ct = 1; ct < 8; ++ct) m = fmaxf(m, acc[ct][r]);
#pragma unroll
        for (int off = 1; off < 32; off <<= 1)
            m = fmaxf(m, __shfl_xor(m, off));
        mx[r] = m;
    }

    __shared__ float red[4][32];
    if (li == 0) {
#pragma unroll
        for (int r = 0; r < 16; ++r)
            red[w][(r & 3) + 8 * (r >> 2) + 4 * hi] = mx[r];
    }
    __syncthreads();
    const float c = 1.44269504f / 32.0f;   // log2(e)/SCALE, SCALE = 32
#pragma unroll
    for (int r = 0; r < 16; ++r) {
        const int row = (r & 3) + 8 * (r >> 2) + 4 * hi;
        float m = fmaxf(fmaxf(red[0][row], red[1][row]),
                        fmaxf(red[2][row], red[3][row]));
        mx[r] = -m * c;
    }
    __syncthreads();

    float sm[16];
#pragma unroll
    for (int r = 0; r < 16; ++r) sm[r] = 0.f;
#pragma unroll
    for (int ct = 0; ct < 8; ++ct) {
#pragma unroll
        for (int r = 0; r < 16; ++r) {
            float p = __builtin_amdgcn_exp2f(fmaf(acc[ct][r], c, mx[r]));
            acc[ct][r] = p;
            sm[r] += p;
        }
    }
#pragma unroll
    for (int r = 0; r < 16; ++r) {
#pragma unroll
        for (int off = 1; off < 32; off <<= 1)
            sm[r] += __shfl_xor(sm[r], off);
    }
    if (li == 0) {
#pragma unroll
        for (int r = 0; r < 16; ++r)
            red[w][(r & 3) + 8 * (r >> 2) + 4 * hi] = sm[r];
    }
    __syncthreads();
#pragma unroll
    for (int r = 0; r < 16; ++r) {
        const int row = (r & 3) + 8 * (r >> 2) + 4 * hi;
        sm[r] = 1.0f / (red[0][row] + red[1][row] + red[2][row] + red[3][row]);
    }

    float* outp = attnOut + (size_t)bh * (Nc * Nc) + (size_t)(rb * 32) * Nc;
#pragma unroll
    for (int ct = 0; ct < 8; ++ct) {
        const int col = colbase + ct * 32 + li;
#pragma unroll
        for (int r = 0; r < 16; ++r) {
            const int row = (r & 3) + 8 * (r >> 2) + 4 * hi;
            __builtin_nontemporal_store(acc[ct][r] * sm[r],
                                        &outp[(size_t)row * Nc + col]);
        }
    }
}

extern "C" void kernel_launch(void* const* d_in, const int* in_sizes, int n_in,
                              void* d_out, int out_size, void* d_ws, size_t ws_size,
                              hipStream_t stream) {
    const float* q  = (const float*)d_in[0];
    const float* k  = (const float*)d_in[1];
    const float* v  = (const float*)d_in[2];
    const float* Wq = (const float*)d_in[3];
    const float* bq = (const float*)d_in[4];
    const float* Wk = (const float*)d_in[5];
    const float* bk = (const float*)d_in[6];
    const float* Wv = (const float*)d_in[7];
    const float* bv = (const float*)d_in[8];

    float* out0 = (float*)d_out;                      // (B,H,N,D) fp32
    float* attn = (float*)d_out + OUT0_ELEMS;         // (B,H,N,N) fp32

    // bf16 scratch in the TAIL of the attn region: proj reads it, then
    // attn_kernel overwrites the whole region. 15M shorts = 30 MB.
    short* s16  = (short*)(attn + SCRATCH_OFF);
    short* xall = s16;                                // Xq|Xk|Xv bf16
    short* wall = s16 + 12582912;                     // Wq|Wk|Wv bf16

    short* qws = (short*)d_ws;                        // bf16 Q [b][h][n][d]
    short* kws = qws + (size_t)Mc * Ec;               // bf16 K [b][h][n][d]

    cvt_kernel<<<dim3(2048, 6), 256, 0, stream>>>(q, k, v, Wq, Wk, Wv, s16);
    proj_kernel<<<dim3(32, 8, 3), 256, 0, stream>>>(
        xall, wall, bq, bk, bv, qws, kws, out0);
    attn_kernel<<<2048, 256, 0, stream>>>(qws, kws, attn);
}